// Round 1
// baseline (3427.687 us; speedup 1.0000x reference)
//
#include <hip/hip_runtime.h>

// PDM (delta-sigma) encode: per row, serial scan
//   x = w/2 + 0.5;  err += x_t;  s_t = err > 0;  err -= s_t
// Must be BIT-EXACT vs the fp32 reference: keep the exact op sequence
//   x = w*0.5f + 0.5f   (w*0.5 exact -> fma-contraction-safe)
//   u = e + x; e = (u > 0) ? u - 1.0f : u
// Latency-bound: 128 independent rows, 160000 dependent steps each.

#define T_LEN 160000
#define CHUNK 64
#define NV (CHUNK / 4)   // float4 per chunk

__device__ __forceinline__ void pdm_step(float v, float& e, float& o) {
    float x = v * 0.5f + 0.5f;   // exact mul -> same rounding as (v/2)+0.5
    float u = e + x;
    bool sp = u > 0.0f;
    o = sp ? 1.0f : 0.0f;
    e = sp ? (u - 1.0f) : u;     // add(u) -> {cmp, u-1} -> cndmask : 3-deep chain
}

__device__ __forceinline__ void pdm_chunk(float4* buf, float& e) {
    #pragma unroll
    for (int i = 0; i < NV; ++i) {
        float4 v = buf[i];
        float r0, r1, r2, r3;
        pdm_step(v.x, e, r0);
        pdm_step(v.y, e, r1);
        pdm_step(v.z, e, r2);
        pdm_step(v.w, e, r3);
        buf[i] = make_float4(r0, r1, r2, r3);   // in-place: reuse regs for output
    }
}

__global__ __launch_bounds__(64, 1)
void pdm_encode(const float* __restrict__ w, float* __restrict__ out, int nRows) {
    int row = blockIdx.x * blockDim.x + threadIdx.x;
    if (row >= nRows) return;

    const float4* __restrict__ src = reinterpret_cast<const float4*>(w + (size_t)row * T_LEN);
    float4* __restrict__ dst = reinterpret_cast<float4*>(out + (size_t)row * T_LEN);

    const int NC = T_LEN / CHUNK;   // 2500 chunks, even

    // Static-named double buffers (no runtime-indexed register arrays).
    float4 A[NV], Bb[NV];

    #pragma unroll
    for (int i = 0; i < NV; ++i) A[i] = src[i];   // prefetch chunk 0

    float e = 0.0f;

    for (int k = 0; k < NC / 2; ++k) {
        const int c0 = 2 * k;
        const int c1 = c0 + 1;

        // prefetch chunk c1 while computing c0
        #pragma unroll
        for (int i = 0; i < NV; ++i) Bb[i] = src[(size_t)c1 * NV + i];

        pdm_chunk(A, e);
        #pragma unroll
        for (int i = 0; i < NV; ++i) dst[(size_t)c0 * NV + i] = A[i];

        // prefetch chunk c0+2 while computing c1
        if (k + 1 < NC / 2) {
            #pragma unroll
            for (int i = 0; i < NV; ++i) A[i] = src[(size_t)(c0 + 2) * NV + i];
        }

        pdm_chunk(Bb, e);
        #pragma unroll
        for (int i = 0; i < NV; ++i) dst[(size_t)c1 * NV + i] = Bb[i];
    }
}

extern "C" void kernel_launch(void* const* d_in, const int* in_sizes, int n_in,
                              void* d_out, int out_size, void* d_ws, size_t ws_size,
                              hipStream_t stream) {
    const float* w = (const float*)d_in[0];
    float* out = (float*)d_out;

    const int nRows = in_sizes[0] / T_LEN;   // B = 128
    const int block = 64;
    const int grid = (nRows + block - 1) / block;

    pdm_encode<<<grid, block, 0, stream>>>(w, out, nRows);
}

// Round 2
// 3237.989 us; speedup vs baseline: 1.0586x; 1.0586x over previous
//
#include <hip/hip_runtime.h>

// PDM (delta-sigma) encode, bit-exact vs fp32 reference:
//   x = w*0.5f + 0.5f  (mul exact -> same rounding as w/2+0.5)
//   u = e + x; s = u>0; e = s ? u-1 : u
// Latency-bound serial scan: 128 rows x 160000 steps. The lever this round:
// sched_barrier(0) fences to stop hipcc sinking prefetch loads into the
// compute chain (R0: VGPR=72 proved the double buffer was dismantled).

#define T_LEN 160000
#define CHUNK 64
#define NV (CHUNK / 4)      // 16 float4 per chunk
#define NC (T_LEN / CHUNK)  // 2500 chunks

__device__ __forceinline__ void pdm_step(float v, float& e, float& o) {
    float x = v * 0.5f + 0.5f;  // off-chain fmac
    float u = e + x;            // chain level 1
    bool sp = u > 0.0f;         // level 2 (cmp), parallel with u-1 (sub)
    o = sp ? 1.0f : 0.0f;       // off-chain cndmask from vcc
    e = sp ? (u - 1.0f) : u;    // level 3 cndmask -> next step's add
}

__device__ __forceinline__ void pdm_chunk(float4* buf, float& e) {
    #pragma unroll
    for (int i = 0; i < NV; ++i) {
        float4 v = buf[i];
        float r0, r1, r2, r3;
        pdm_step(v.x, e, r0);
        pdm_step(v.y, e, r1);
        pdm_step(v.z, e, r2);
        pdm_step(v.w, e, r3);
        buf[i] = make_float4(r0, r1, r2, r3);  // in-place: reuse regs for output
    }
}

__global__ __launch_bounds__(64, 1)
void pdm_encode(const float* __restrict__ w, float* __restrict__ out, int nRows) {
    const int row = blockIdx.x * 64 + threadIdx.x;
    if (row >= nRows) return;

    const float4* __restrict__ src = reinterpret_cast<const float4*>(w + (size_t)row * T_LEN);
    float4* __restrict__ dst = reinterpret_cast<float4*>(out + (size_t)row * T_LEN);

    float4 A[NV], B[NV];   // static-named double buffers (no runtime indexing)

    #pragma unroll
    for (int i = 0; i < NV; ++i) A[i] = src[i];   // prefetch chunk 0
    __builtin_amdgcn_sched_barrier(0);

    float e = 0.0f;

    for (int k = 0; k < NC / 2 - 1; ++k) {
        const int c0 = 2 * k;
        const int c1 = c0 + 1;

        // prefetch c1 -> B, pinned BEFORE compute of A
        #pragma unroll
        for (int i = 0; i < NV; ++i) B[i] = src[c1 * NV + i];
        __builtin_amdgcn_sched_barrier(0);

        pdm_chunk(A, e);                 // ~64 steps of serial chain hides load latency
        __builtin_amdgcn_sched_barrier(0);

        #pragma unroll
        for (int i = 0; i < NV; ++i) dst[c0 * NV + i] = A[i];
        __builtin_amdgcn_sched_barrier(0);

        // prefetch c0+2 -> A, pinned BEFORE compute of B
        #pragma unroll
        for (int i = 0; i < NV; ++i) A[i] = src[(c0 + 2) * NV + i];
        __builtin_amdgcn_sched_barrier(0);

        pdm_chunk(B, e);
        __builtin_amdgcn_sched_barrier(0);

        #pragma unroll
        for (int i = 0; i < NV; ++i) dst[c1 * NV + i] = B[i];
        __builtin_amdgcn_sched_barrier(0);
    }

    // tail pair: no further prefetch
    {
        const int c0 = NC - 2;
        const int c1 = NC - 1;
        #pragma unroll
        for (int i = 0; i < NV; ++i) B[i] = src[c1 * NV + i];
        __builtin_amdgcn_sched_barrier(0);
        pdm_chunk(A, e);
        #pragma unroll
        for (int i = 0; i < NV; ++i) dst[c0 * NV + i] = A[i];
        pdm_chunk(B, e);
        #pragma unroll
        for (int i = 0; i < NV; ++i) dst[c1 * NV + i] = B[i];
    }
}

extern "C" void kernel_launch(void* const* d_in, const int* in_sizes, int n_in,
                              void* d_out, int out_size, void* d_ws, size_t ws_size,
                              hipStream_t stream) {
    const float* w = (const float*)d_in[0];
    float* out = (float*)d_out;

    const int nRows = in_sizes[0] / T_LEN;   // B = 128
    const int block = 64;
    const int grid = (nRows + block - 1) / block;  // 2 blocks

    pdm_encode<<<grid, block, 0, stream>>>(w, out, nRows);
}